// Round 1
// baseline (475.162 us; speedup 1.0000x reference)
//
#include <hip/hip_runtime.h>
#include <hip/hip_bf16.h>
#include <cstdint>
#include <cstddef>

// Problem constants
#define B_SZ 4096
#define T_SZ 4
#define C_SZ 1024
#define H_SZ 8
#define DH_SZ 128
#define NQKV 3072                      // 3*C
#define SCALE_F 0.08838834764831845f   // 128^-0.5

typedef float f32x4 __attribute__((ext_vector_type(4)));
typedef short s16x8 __attribute__((ext_vector_type(8)));

static __device__ __forceinline__ float bf2f(unsigned short u) {
    union { unsigned int i; float f; } x; x.i = ((unsigned int)u) << 16; return x.f;
}
static __device__ __forceinline__ unsigned short f2bf(float f) {
    union { unsigned int i; float f; } x; x.f = f;
    unsigned int r = x.i + 0x7FFFu + ((x.i >> 16) & 1u);   // RNE
    return (unsigned short)(r >> 16);
}

// ---------------- elementwise fp32 -> bf16 ----------------
__global__ __launch_bounds__(256) void cvt_f32_bf16(const float* __restrict__ src,
                                                    unsigned short* __restrict__ dst, int n4) {
    int i = blockIdx.x * 256 + threadIdx.x;
    if (i >= n4) return;
    float4 v = reinterpret_cast<const float4*>(src)[i];
    ushort4 o;
    o.x = f2bf(v.x); o.y = f2bf(v.y); o.z = f2bf(v.z); o.w = f2bf(v.w);
    reinterpret_cast<ushort4*>(dst)[i] = o;
}

// ---------------- transpose + convert: src[K][N] fp32 -> dst[N][K] bf16 (per z=task) --------
__global__ __launch_bounds__(256) void transpose_cvt(const float* __restrict__ src,
                                                     unsigned short* __restrict__ dst,
                                                     int K, int N) {
    __shared__ float tile[32][33];
    const float* s = src + (size_t)blockIdx.z * K * N;
    unsigned short* d = dst + (size_t)blockIdx.z * K * N;
    int n0 = blockIdx.x * 32, k0 = blockIdx.y * 32;
    int tx = threadIdx.x, ty = threadIdx.y;
#pragma unroll
    for (int i = 0; i < 4; i++) {
        int k = k0 + ty + i * 8;
        tile[ty + i * 8][tx] = s[(size_t)k * N + n0 + tx];
    }
    __syncthreads();
#pragma unroll
    for (int i = 0; i < 4; i++) {
        int n = n0 + ty + i * 8;
        d[(size_t)n * K + k0 + tx] = f2bf(tile[tx][ty + i * 8]);
    }
}

// ---------------- bf16 MFMA GEMM ----------------
// A: bf16, row m of task t at A + t*C + m*(T*C), K = C = 1024
// Bt: bf16 [T][NSIZE][K] (B transposed), bias: fp32 [T][NSIZE]
// EPI 0: out_bf[(m*T+t)*NSIZE + n] = bf16(acc + bias)
// EPI 1: out_f [(m*T+t)*NSIZE + n] = acc + bias + resid[(m*T+t)*NSIZE + n]
template<int NSIZE, int EPI>
__global__ __launch_bounds__(256) void gemm_bf16(
    const unsigned short* __restrict__ A,
    const unsigned short* __restrict__ Bt,
    const float* __restrict__ bias,
    const float* __restrict__ resid,
    unsigned short* __restrict__ out_bf,
    float* __restrict__ out_f)
{
    constexpr int BM = 128, BN = 128, BK = 32, LDK = BK + 8;
    __shared__ short lA[BM][LDK];
    __shared__ short lB[BN][LDK];

    const int t   = blockIdx.z;
    const int m0  = blockIdx.y * BM;
    const int n0  = blockIdx.x * BN;
    const int tid = threadIdx.x;
    const int lane = tid & 63;
    const int wave = tid >> 6;
    const int wm = (wave >> 1) * 64;
    const int wn = (wave & 1) * 64;
    const int quad = lane >> 4;
    const int l16  = lane & 15;

    const unsigned short* Abase = A + (size_t)t * C_SZ;
    const unsigned short* Bbase = Bt + (size_t)t * NSIZE * C_SZ;

    f32x4 acc[4][4] = {};

    for (int kk = 0; kk < C_SZ; kk += BK) {
#pragma unroll
        for (int s = 0; s < 2; s++) {
            int slot = tid + s * 256;          // 512 slots: 128 rows x 4 chunks of 8 elems
            int r  = slot >> 2;
            int ko = (slot & 3) * 8;
            s16x8 va = *reinterpret_cast<const s16x8*>(
                Abase + (size_t)(m0 + r) * (T_SZ * C_SZ) + kk + ko);
            *reinterpret_cast<s16x8*>(&lA[r][ko]) = va;
            s16x8 vb = *reinterpret_cast<const s16x8*>(
                Bbase + (size_t)(n0 + r) * C_SZ + kk + ko);
            *reinterpret_cast<s16x8*>(&lB[r][ko]) = vb;
        }
        __syncthreads();

        s16x8 af[4], bfr[4];
#pragma unroll
        for (int mi = 0; mi < 4; mi++)
            af[mi] = *reinterpret_cast<const s16x8*>(&lA[wm + mi * 16 + l16][quad * 8]);
#pragma unroll
        for (int ni = 0; ni < 4; ni++)
            bfr[ni] = *reinterpret_cast<const s16x8*>(&lB[wn + ni * 16 + l16][quad * 8]);
#pragma unroll
        for (int mi = 0; mi < 4; mi++)
#pragma unroll
            for (int ni = 0; ni < 4; ni++)
                acc[mi][ni] = __builtin_amdgcn_mfma_f32_16x16x32_bf16(
                    af[mi], bfr[ni], acc[mi][ni], 0, 0, 0);
        __syncthreads();
    }

    // Epilogue. C/D layout: col = lane&15, row = quad*4 + reg  [verified m89/m91]
#pragma unroll
    for (int ni = 0; ni < 4; ni++) {
        int gn = n0 + wn + ni * 16 + l16;
        float bi = bias[t * NSIZE + gn];
#pragma unroll
        for (int mi = 0; mi < 4; mi++) {
#pragma unroll
            for (int r = 0; r < 4; r++) {
                int gm = m0 + wm + mi * 16 + quad * 4 + r;
                size_t o = (size_t)(gm * T_SZ + t) * NSIZE + gn;
                float v = acc[mi][ni][r] + bi;
                if (EPI == 0) {
                    out_bf[o] = f2bf(v);
                } else {
                    out_f[o] = v + resid[o];
                }
            }
        }
    }
}

// ---------------- cross-task attention: one wave per (b, h) ----------------
// qkv: bf16 [B][T][3C]; ctx: bf16 [B][T][C]
__global__ __launch_bounds__(256) void attn_kernel(const unsigned short* __restrict__ qkv,
                                                   unsigned short* __restrict__ ctx) {
    int wave = threadIdx.x >> 6, lane = threadIdx.x & 63;
    int g = blockIdx.x * 4 + wave;     // [0, B*H)
    int b = g >> 3, h = g & 7;
    int d0 = lane * 2;                 // each lane owns 2 of DH=128 dims

    const unsigned short* base = qkv + (size_t)b * T_SZ * NQKV + h * DH_SZ + d0;
    float qf[4][2], kf[4][2], vf[4][2];
#pragma unroll
    for (int i = 0; i < 4; i++) {
        const unsigned short* p = base + (size_t)i * NQKV;
        qf[i][0] = bf2f(p[0]);          qf[i][1] = bf2f(p[1]);
        kf[i][0] = bf2f(p[C_SZ]);       kf[i][1] = bf2f(p[C_SZ + 1]);
        vf[i][0] = bf2f(p[2 * C_SZ]);   vf[i][1] = bf2f(p[2 * C_SZ + 1]);
    }
    float s[4][4];
#pragma unroll
    for (int i = 0; i < 4; i++)
#pragma unroll
        for (int j = 0; j < 4; j++) {
            float p = qf[i][0] * kf[j][0] + qf[i][1] * kf[j][1];
#pragma unroll
            for (int off = 32; off > 0; off >>= 1) p += __shfl_xor(p, off);
            s[i][j] = p * SCALE_F;
        }
#pragma unroll
    for (int i = 0; i < 4; i++) {
        float m = fmaxf(fmaxf(s[i][0], s[i][1]), fmaxf(s[i][2], s[i][3]));
        float e0 = __expf(s[i][0] - m), e1 = __expf(s[i][1] - m);
        float e2 = __expf(s[i][2] - m), e3 = __expf(s[i][3] - m);
        float inv = 1.0f / (e0 + e1 + e2 + e3);
        s[i][0] = e0 * inv; s[i][1] = e1 * inv; s[i][2] = e2 * inv; s[i][3] = e3 * inv;
    }
#pragma unroll
    for (int i = 0; i < 4; i++) {
        float o0 = s[i][0] * vf[0][0] + s[i][1] * vf[1][0] + s[i][2] * vf[2][0] + s[i][3] * vf[3][0];
        float o1 = s[i][0] * vf[0][1] + s[i][1] * vf[1][1] + s[i][2] * vf[2][1] + s[i][3] * vf[3][1];
        size_t o = (size_t)(b * T_SZ + i) * C_SZ + h * DH_SZ + d0;
        ctx[o] = f2bf(o0); ctx[o + 1] = f2bf(o1);
    }
}

// ---------------- LayerNorm over C, one block per (b,t) row ----------------
__global__ __launch_bounds__(256) void ln_kernel(const float* __restrict__ y,
                                                 const float* __restrict__ gamma,
                                                 const float* __restrict__ beta,
                                                 float* __restrict__ out) {
    int row = blockIdx.x;
    int lane = threadIdx.x & 63, wave = threadIdx.x >> 6;
    float4 v = reinterpret_cast<const float4*>(y + (size_t)row * C_SZ)[threadIdx.x];
    float s  = v.x + v.y + v.z + v.w;
    float ss = v.x * v.x + v.y * v.y + v.z * v.z + v.w * v.w;
#pragma unroll
    for (int off = 32; off > 0; off >>= 1) { s += __shfl_xor(s, off); ss += __shfl_xor(ss, off); }
    __shared__ float red[8];
    if (lane == 0) { red[wave] = s; red[wave + 4] = ss; }
    __syncthreads();
    float S  = red[0] + red[1] + red[2] + red[3];
    float SS = red[4] + red[5] + red[6] + red[7];
    float mean = S * (1.0f / C_SZ);
    float var  = SS * (1.0f / C_SZ) - mean * mean;
    float inv  = rsqrtf(var + 1e-5f);
    float4 g  = reinterpret_cast<const float4*>(gamma)[threadIdx.x];
    float4 be = reinterpret_cast<const float4*>(beta)[threadIdx.x];
    float4 o;
    o.x = (v.x - mean) * inv * g.x + be.x;
    o.y = (v.y - mean) * inv * g.y + be.y;
    o.z = (v.z - mean) * inv * g.z + be.z;
    o.w = (v.w - mean) * inv * g.w + be.w;
    reinterpret_cast<float4*>(out + (size_t)row * C_SZ)[threadIdx.x] = o;
}

extern "C" void kernel_launch(void* const* d_in, const int* in_sizes, int n_in,
                              void* d_out, int out_size, void* d_ws, size_t ws_size,
                              hipStream_t stream) {
    const float* feats = (const float*)d_in[0];   // [B,T,C]
    const float* Wqkv  = (const float*)d_in[1];   // [T,C,3C]
    const float* bqkv  = (const float*)d_in[2];   // [T,3C]
    const float* Wproj = (const float*)d_in[3];   // [T,C,C]
    const float* bproj = (const float*)d_in[4];   // [T,C]
    const float* gamma = (const float*)d_in[5];   // [C]
    const float* beta  = (const float*)d_in[6];   // [C]
    float* out = (float*)d_out;

    // ws layout (bytes):
    //   [0,   33.5M)  feats_bf16  [B,T,C]
    //   [33.5M, 58.7M) WqkvT bf16 [T,3C,C]
    //   [58.7M, 67.1M) WprojT bf16 [T,C,C]
    //   [67.1M, 167.8M) qkv bf16 [B,T,3C]   (later aliased by y fp32 [B,T,C] = 67.1MB)
    //   [167.8M, 201.3M) ctx bf16 [B,T,C]
    char* ws = (char*)d_ws;
    unsigned short* feats_bf = (unsigned short*)(ws);
    unsigned short* wqkv_t   = (unsigned short*)(ws + 33554432);
    unsigned short* wproj_t  = (unsigned short*)(ws + 58720256);
    unsigned short* qkv      = (unsigned short*)(ws + 67108864);
    unsigned short* ctx      = (unsigned short*)(ws + 167772160);
    float* ybuf              = (float*)(ws + 67108864);   // aliases qkv (dead after attn)

    cvt_f32_bf16<<<16384, 256, 0, stream>>>(feats, feats_bf, (B_SZ * T_SZ * C_SZ) / 4);
    transpose_cvt<<<dim3(96, 32, 4), dim3(32, 8), 0, stream>>>(Wqkv, wqkv_t, C_SZ, NQKV);
    transpose_cvt<<<dim3(32, 32, 4), dim3(32, 8), 0, stream>>>(Wproj, wproj_t, C_SZ, C_SZ);

    gemm_bf16<NQKV, 0><<<dim3(NQKV / 128, B_SZ / 128, T_SZ), 256, 0, stream>>>(
        feats_bf, wqkv_t, bqkv, nullptr, qkv, nullptr);

    attn_kernel<<<(B_SZ * H_SZ) / 4, 256, 0, stream>>>(qkv, ctx);

    gemm_bf16<C_SZ, 1><<<dim3(C_SZ / 128, B_SZ / 128, T_SZ), 256, 0, stream>>>(
        ctx, wproj_t, bproj, feats, nullptr, ybuf);

    ln_kernel<<<B_SZ * T_SZ, 256, 0, stream>>>(ybuf, gamma, beta, out);
}

// Round 2
// 443.984 us; speedup vs baseline: 1.0702x; 1.0702x over previous
//
#include <hip/hip_runtime.h>
#include <hip/hip_bf16.h>
#include <cstdint>
#include <cstddef>

// Problem constants
#define B_SZ 4096
#define T_SZ 4
#define C_SZ 1024
#define H_SZ 8
#define DH_SZ 128
#define NQKV 3072                      // 3*C
#define SCALE_F 0.08838834764831845f   // 128^-0.5

typedef float f32x4 __attribute__((ext_vector_type(4)));
typedef short s16x8 __attribute__((ext_vector_type(8)));

static __device__ __forceinline__ float bf2f(unsigned short u) {
    union { unsigned int i; float f; } x; x.i = ((unsigned int)u) << 16; return x.f;
}
static __device__ __forceinline__ unsigned short f2bf(float f) {
    union { unsigned int i; float f; } x; x.f = f;
    unsigned int r = x.i + 0x7FFFu + ((x.i >> 16) & 1u);   // RNE
    return (unsigned short)(r >> 16);
}

// async global->LDS, 16B per lane; lds base must be wave-uniform (HW adds lane*16)
typedef const __attribute__((address_space(1))) void* gas_ptr;
typedef __attribute__((address_space(3))) void* las_ptr;
static __device__ __forceinline__ void async16(const void* g, void* l) {
    __builtin_amdgcn_global_load_lds((gas_ptr)g, (las_ptr)l, 16, 0, 0);
}

// ---------------- elementwise fp32 -> bf16 ----------------
__global__ __launch_bounds__(256) void cvt_f32_bf16(const float* __restrict__ src,
                                                    unsigned short* __restrict__ dst, int n4) {
    int i = blockIdx.x * 256 + threadIdx.x;
    if (i >= n4) return;
    float4 v = reinterpret_cast<const float4*>(src)[i];
    ushort4 o;
    o.x = f2bf(v.x); o.y = f2bf(v.y); o.z = f2bf(v.z); o.w = f2bf(v.w);
    reinterpret_cast<ushort4*>(dst)[i] = o;
}

// ---------------- transpose + convert: src[K][N] fp32 -> dst[N][K] bf16 (per z=task) --------
__global__ __launch_bounds__(256) void transpose_cvt(const float* __restrict__ src,
                                                     unsigned short* __restrict__ dst,
                                                     int K, int N) {
    __shared__ float tile[32][33];
    const float* s = src + (size_t)blockIdx.z * K * N;
    unsigned short* d = dst + (size_t)blockIdx.z * K * N;
    int n0 = blockIdx.x * 32, k0 = blockIdx.y * 32;
    int tx = threadIdx.x, ty = threadIdx.y;
#pragma unroll
    for (int i = 0; i < 4; i++) {
        int k = k0 + ty + i * 8;
        tile[ty + i * 8][tx] = s[(size_t)k * N + n0 + tx];
    }
    __syncthreads();
#pragma unroll
    for (int i = 0; i < 4; i++) {
        int n = n0 + ty + i * 8;
        d[(size_t)n * K + k0 + tx] = f2bf(tile[tx][ty + i * 8]);
    }
}

// ---------------- bf16 MFMA GEMM with global_load_lds staging ----------------
// A: bf16, row m of task t at A + t*C + m*(T*C), K = C = 1024
// Bt: bf16 [T][NSIZE][K] (B transposed), bias: fp32 [T][NSIZE]
// EPI 0: out_bf[(m*T+t)*NSIZE + n] = bf16(acc + bias)
// EPI 1: out_f [(m*T+t)*NSIZE + n] = acc + bias + resid[(m*T+t)*NSIZE + n]
//
// LDS layout (per tile, 128 rows x 32 shorts, NO pad — required by global_load_lds):
//   addr(row, chunk) = row*32 + (chunk ^ (row&3))*8 shorts   (chunk = 8-short k-group)
//   staging slot s (0..511): row = s>>2, stored-chunk = s&3, data-chunk = (s&3)^(row&3)
//   -> ds_read_b128 fragment reads are <=2-way per 8-lane phase (free, m136)
template<int NSIZE, int EPI>
__global__ __launch_bounds__(256) void gemm_bf16(
    const unsigned short* __restrict__ A,
    const unsigned short* __restrict__ Bt,
    const float* __restrict__ bias,
    const float* __restrict__ resid,
    unsigned short* __restrict__ out_bf,
    float* __restrict__ out_f)
{
    constexpr int BM = 128, BN = 128, BK = 32;
    __shared__ unsigned short lA[BM * BK];
    __shared__ unsigned short lB[BN * BK];

    const int t   = blockIdx.z;
    const int m0  = blockIdx.y * BM;
    const int n0  = blockIdx.x * BN;
    const int tid = threadIdx.x;
    const int lane = tid & 63;
    const int wave = tid >> 6;
    const int wm = (wave >> 1) * 64;
    const int wn = (wave & 1) * 64;
    const int quad = lane >> 4;
    const int l16  = lane & 15;

    const unsigned short* Abase = A + (size_t)t * C_SZ;
    const unsigned short* Bbase = Bt + (size_t)t * NSIZE * C_SZ;

    // staging: 8 instructions each for A and B per k-iter; wave w issues insts {2w, 2w+1}
    const int j0 = wave * 2;
    const unsigned short* gA[2];
    const unsigned short* gB[2];
    unsigned short* lAdst[2];
    unsigned short* lBdst[2];
#pragma unroll
    for (int j = 0; j < 2; j++) {
        int slot = (j0 + j) * 64 + lane;
        int row = slot >> 2;
        int ch  = (slot & 3) ^ (row & 3);
        gA[j] = Abase + (size_t)(m0 + row) * (T_SZ * C_SZ) + ch * 8;
        gB[j] = Bbase + (size_t)(n0 + row) * C_SZ + ch * 8;
        lAdst[j] = &lA[(j0 + j) * 512];   // wave-uniform base
        lBdst[j] = &lB[(j0 + j) * 512];
    }

    // fragment read pointers (loop-invariant): row&3 == l16&3 for every mi/ni
    const int sw = quad ^ (l16 & 3);
    const s16x8* aP[4];
    const s16x8* bP[4];
#pragma unroll
    for (int i = 0; i < 4; i++) {
        aP[i] = reinterpret_cast<const s16x8*>(&lA[(wm + i * 16 + l16) * BK + sw * 8]);
        bP[i] = reinterpret_cast<const s16x8*>(&lB[(wn + i * 16 + l16) * BK + sw * 8]);
    }

    f32x4 acc[4][4] = {};

    for (int kk = 0; kk < C_SZ; kk += BK) {
        async16(gA[0] + kk, lAdst[0]);
        async16(gA[1] + kk, lAdst[1]);
        async16(gB[0] + kk, lBdst[0]);
        async16(gB[1] + kk, lBdst[1]);
        __syncthreads();

        s16x8 af[4], bfr[4];
#pragma unroll
        for (int i = 0; i < 4; i++) { af[i] = *aP[i]; bfr[i] = *bP[i]; }
#pragma unroll
        for (int mi = 0; mi < 4; mi++)
#pragma unroll
            for (int ni = 0; ni < 4; ni++)
                acc[mi][ni] = __builtin_amdgcn_mfma_f32_16x16x32_bf16(
                    af[mi], bfr[ni], acc[mi][ni], 0, 0, 0);
        __syncthreads();
    }

    // Epilogue. C/D layout: col = lane&15, row = quad*4 + reg  [verified m89/m91]
#pragma unroll
    for (int ni = 0; ni < 4; ni++) {
        int gn = n0 + wn + ni * 16 + l16;
        float bi = bias[t * NSIZE + gn];
#pragma unroll
        for (int mi = 0; mi < 4; mi++) {
#pragma unroll
            for (int r = 0; r < 4; r++) {
                int gm = m0 + wm + mi * 16 + quad * 4 + r;
                size_t o = (size_t)(gm * T_SZ + t) * NSIZE + gn;
                float v = acc[mi][ni][r] + bi;
                if (EPI == 0) {
                    out_bf[o] = f2bf(v);
                } else {
                    out_f[o] = v + resid[o];
                }
            }
        }
    }
}

// ---------------- cross-task attention: one wave per (b, h) ----------------
// qkv: bf16 [B][T][3C]; ctx: bf16 [B][T][C]
__global__ __launch_bounds__(256) void attn_kernel(const unsigned short* __restrict__ qkv,
                                                   unsigned short* __restrict__ ctx) {
    int wave = threadIdx.x >> 6, lane = threadIdx.x & 63;
    int g = blockIdx.x * 4 + wave;     // [0, B*H)
    int b = g >> 3, h = g & 7;
    int d0 = lane * 2;                 // each lane owns 2 of DH=128 dims

    const unsigned short* base = qkv + (size_t)b * T_SZ * NQKV + h * DH_SZ + d0;
    float qf[4][2], kf[4][2], vf[4][2];
#pragma unroll
    for (int i = 0; i < 4; i++) {
        const unsigned short* p = base + (size_t)i * NQKV;
        qf[i][0] = bf2f(p[0]);          qf[i][1] = bf2f(p[1]);
        kf[i][0] = bf2f(p[C_SZ]);       kf[i][1] = bf2f(p[C_SZ + 1]);
        vf[i][0] = bf2f(p[2 * C_SZ]);   vf[i][1] = bf2f(p[2 * C_SZ + 1]);
    }
    float s[4][4];
#pragma unroll
    for (int i = 0; i < 4; i++)
#pragma unroll
        for (int j = 0; j < 4; j++) {
            float p = qf[i][0] * kf[j][0] + qf[i][1] * kf[j][1];
#pragma unroll
            for (int off = 32; off > 0; off >>= 1) p += __shfl_xor(p, off);
            s[i][j] = p * SCALE_F;
        }
#pragma unroll
    for (int i = 0; i < 4; i++) {
        float m = fmaxf(fmaxf(s[i][0], s[i][1]), fmaxf(s[i][2], s[i][3]));
        float e0 = __expf(s[i][0] - m), e1 = __expf(s[i][1] - m);
        float e2 = __expf(s[i][2] - m), e3 = __expf(s[i][3] - m);
        float inv = 1.0f / (e0 + e1 + e2 + e3);
        s[i][0] = e0 * inv; s[i][1] = e1 * inv; s[i][2] = e2 * inv; s[i][3] = e3 * inv;
    }
#pragma unroll
    for (int i = 0; i < 4; i++) {
        float o0 = s[i][0] * vf[0][0] + s[i][1] * vf[1][0] + s[i][2] * vf[2][0] + s[i][3] * vf[3][0];
        float o1 = s[i][0] * vf[0][1] + s[i][1] * vf[1][1] + s[i][2] * vf[2][1] + s[i][3] * vf[3][1];
        size_t o = (size_t)(b * T_SZ + i) * C_SZ + h * DH_SZ + d0;
        ctx[o] = f2bf(o0); ctx[o + 1] = f2bf(o1);
    }
}

// ---------------- LayerNorm over C, one block per (b,t) row ----------------
__global__ __launch_bounds__(256) void ln_kernel(const float* __restrict__ y,
                                                 const float* __restrict__ gamma,
                                                 const float* __restrict__ beta,
                                                 float* __restrict__ out) {
    int row = blockIdx.x;
    int lane = threadIdx.x & 63, wave = threadIdx.x >> 6;
    float4 v = reinterpret_cast<const float4*>(y + (size_t)row * C_SZ)[threadIdx.x];
    float s  = v.x + v.y + v.z + v.w;
    float ss = v.x * v.x + v.y * v.y + v.z * v.z + v.w * v.w;
#pragma unroll
    for (int off = 32; off > 0; off >>= 1) { s += __shfl_xor(s, off); ss += __shfl_xor(ss, off); }
    __shared__ float red[8];
    if (lane == 0) { red[wave] = s; red[wave + 4] = ss; }
    __syncthreads();
    float S  = red[0] + red[1] + red[2] + red[3];
    float SS = red[4] + red[5] + red[6] + red[7];
    float mean = S * (1.0f / C_SZ);
    float var  = SS * (1.0f / C_SZ) - mean * mean;
    float inv  = rsqrtf(var + 1e-5f);
    float4 g  = reinterpret_cast<const float4*>(gamma)[threadIdx.x];
    float4 be = reinterpret_cast<const float4*>(beta)[threadIdx.x];
    float4 o;
    o.x = (v.x - mean) * inv * g.x + be.x;
    o.y = (v.y - mean) * inv * g.y + be.y;
    o.z = (v.z - mean) * inv * g.z + be.z;
    o.w = (v.w - mean) * inv * g.w + be.w;
    reinterpret_cast<float4*>(out + (size_t)row * C_SZ)[threadIdx.x] = o;
}

extern "C" void kernel_launch(void* const* d_in, const int* in_sizes, int n_in,
                              void* d_out, int out_size, void* d_ws, size_t ws_size,
                              hipStream_t stream) {
    const float* feats = (const float*)d_in[0];   // [B,T,C]
    const float* Wqkv  = (const float*)d_in[1];   // [T,C,3C]
    const float* bqkv  = (const float*)d_in[2];   // [T,3C]
    const float* Wproj = (const float*)d_in[3];   // [T,C,C]
    const float* bproj = (const float*)d_in[4];   // [T,C]
    const float* gamma = (const float*)d_in[5];   // [C]
    const float* beta  = (const float*)d_in[6];   // [C]
    float* out = (float*)d_out;

    // ws layout (bytes):
    //   [0,   33.5M)  feats_bf16  [B,T,C]
    //   [33.5M, 58.7M) WqkvT bf16 [T,3C,C]
    //   [58.7M, 67.1M) WprojT bf16 [T,C,C]
    //   [67.1M, 167.8M) qkv bf16 [B,T,3C]   (later aliased by y fp32 [B,T,C] = 67.1MB)
    //   [167.8M, 201.3M) ctx bf16 [B,T,C]
    char* ws = (char*)d_ws;
    unsigned short* feats_bf = (unsigned short*)(ws);
    unsigned short* wqkv_t   = (unsigned short*)(ws + 33554432);
    unsigned short* wproj_t  = (unsigned short*)(ws + 58720256);
    unsigned short* qkv      = (unsigned short*)(ws + 67108864);
    unsigned short* ctx      = (unsigned short*)(ws + 167772160);
    float* ybuf              = (float*)(ws + 67108864);   // aliases qkv (dead after attn)

    cvt_f32_bf16<<<16384, 256, 0, stream>>>(feats, feats_bf, (B_SZ * T_SZ * C_SZ) / 4);
    transpose_cvt<<<dim3(96, 32, 4), dim3(32, 8), 0, stream>>>(Wqkv, wqkv_t, C_SZ, NQKV);
    transpose_cvt<<<dim3(32, 32, 4), dim3(32, 8), 0, stream>>>(Wproj, wproj_t, C_SZ, C_SZ);

    gemm_bf16<NQKV, 0><<<dim3(NQKV / 128, B_SZ / 128, T_SZ), 256, 0, stream>>>(
        feats_bf, wqkv_t, bqkv, nullptr, qkv, nullptr);

    attn_kernel<<<(B_SZ * H_SZ) / 4, 256, 0, stream>>>(qkv, ctx);

    gemm_bf16<C_SZ, 1><<<dim3(C_SZ / 128, B_SZ / 128, T_SZ), 256, 0, stream>>>(
        ctx, wproj_t, bproj, feats, nullptr, ybuf);

    ln_kernel<<<B_SZ * T_SZ, 256, 0, stream>>>(ybuf, gamma, beta, out);
}